// Round 1
// 433.231 us; speedup vs baseline: 1.2616x; 1.2616x over previous
//
#include <hip/hip_runtime.h>

// ============================================================================
// Fused 2-layer transformer encoder (B=1024, T=128, D=128, H=8, HD=16, FF=512)
// One workgroup per batch element; activations resident in LDS; bf16 MFMA
// 16x16x32 for every matmul; fp32 accumulation/softmax/LN.
//
// This revision attacks the LDS-pipe bound: every projection is computed in
// the TRANSPOSED orientation (Y^T = W * X^T) so MFMA C-fragments pack as
// 4 consecutive columns of the [t][d] buffers -> all LDS stores are ushort4,
// softmax rows are per-lane (swapped QK^T, mask+scale folded into the MFMA
// via the zero-padded K slots), LN reductions need only 2 shuffles, and each
// wave's K/V fragments are hoisted into registers once per layer.
// Tiles use stride 128 + 16B-unit XOR swizzle (col ^= (row&7)<<3).
// ============================================================================

typedef __attribute__((ext_vector_type(8))) __bf16 bf16x8;
typedef __attribute__((ext_vector_type(4))) float fx4;

#define MFMA16(a, b, c) __builtin_amdgcn_mfma_f32_16x16x32_bf16((a), (b), (c), 0, 0, 0)

static __device__ __forceinline__ unsigned short f2bf(float f) {
    __bf16 b = (__bf16)f;                       // fptrunc f32->bf16, RTN-even
    return __builtin_bit_cast(unsigned short, b);
}
static __device__ __forceinline__ float bf2f(unsigned short u) {
    return (float)__builtin_bit_cast(__bf16, u);
}
// element index into a [128][128] tile, 16B-unit XOR swizzle on the row
static __device__ __forceinline__ int swz(int row, int col) {
    return (row << 7) + (col ^ ((row & 7) << 3));
}
// same for the [128][256] FF-hidden tile
static __device__ __forceinline__ int swzh(int row, int col) {
    return (row << 8) + (col ^ ((row & 7) << 3));
}

// --------------------------------------------------------------------------
// Prep: convert all fp32 weights to bf16 into workspace.
// Segments (elements): in_proj 98304 | out 32768 | ff1 131072 | ff2 131072
// --------------------------------------------------------------------------
extern "C" __global__ void prep_weights_bf16(const float* __restrict__ w_in,
                                             const float* __restrict__ w_out,
                                             const float* __restrict__ w_ff1,
                                             const float* __restrict__ w_ff2,
                                             unsigned short* __restrict__ ws) {
    int i = blockIdx.x * 256 + threadIdx.x;     // grid covers exactly 393216
    float v;
    if (i < 98304)       v = w_in[i];
    else if (i < 131072) v = w_out[i - 98304];
    else if (i < 262144) v = w_ff1[i - 131072];
    else                 v = w_ff2[i - 262144];
    ws[i] = f2bf(v);
}

// --------------------------------------------------------------------------
// Main fused kernel. block = 512 threads = 8 waves. grid = 1024 (one per b).
// --------------------------------------------------------------------------
extern "C" __global__ void __launch_bounds__(512, 2)
fused_transformer(const float* __restrict__ x,
                  const float* __restrict__ mask,
                  const float* __restrict__ inp_b,
                  const float* __restrict__ out_b,
                  const float* __restrict__ ln1g, const float* __restrict__ ln1b,
                  const float* __restrict__ ff1b, const float* __restrict__ ff2b,
                  const float* __restrict__ ln2g, const float* __restrict__ ln2b,
                  const unsigned short* __restrict__ w_inp,
                  const unsigned short* __restrict__ w_out,
                  const unsigned short* __restrict__ w_ff1,
                  const unsigned short* __restrict__ w_ff2,
                  float* __restrict__ out) {
    // 146 KiB static LDS
    __shared__ __align__(16) unsigned short xs[16384];   // x / LN outputs [t][d]
    __shared__ __align__(16) unsigned short qs[16384];   // q -> o          [t][d]
    __shared__ __align__(16) unsigned short kvh[32768];  // k | v^T ; FF hidden
    __shared__ __align__(16) unsigned short ps[9216];    // per-wave P [16][72]; LN alias

    unsigned short* ksb = kvh;             // k  [t][d]
    unsigned short* vtb = kvh + 16384;     // v^T [d][t]
    float2* lnp = (float2*)ps;             // [8][128] {sum, sumsq}
    float2* mrp = lnp + 1024;              // [128] {mean, rstd}

    const int tid = threadIdx.x;
    const int w   = tid >> 6;        // wave 0..7 (== head in phase B)
    const int lid = tid & 63;
    const int l15 = lid & 15;
    const int kg  = lid >> 4;        // k-group 0..3
    const int b   = blockIdx.x;

    // ---- stage x[b] (fp32 global) -> xs (bf16 LDS, swizzled) ----
    const float* xb = x + (size_t)b * 16384;
    #pragma unroll
    for (int i = 0; i < 8; ++i) {
        int e = i * 2048 + tid * 4;
        float4 v4 = *(const float4*)(xb + e);
        int row = e >> 7, col = e & 127;
        ushort4 pk;
        pk.x = f2bf(v4.x); pk.y = f2bf(v4.y); pk.z = f2bf(v4.z); pk.w = f2bf(v4.w);
        *(ushort4*)(xs + swz(row, col)) = pk;
    }
    // additive key mask, key = nt*16 + l15 (per-lane, reused for both layers)
    float mreg[8];
    #pragma unroll
    for (int nt = 0; nt < 8; ++nt) mreg[nt] = mask[b * 128 + nt * 16 + l15];

    __syncthreads();

    for (int l = 0; l < 2; ++l) {
        // ========== Phase A: QKV projection (transposed orientation) ========
        // wave w computes exactly head w's q, k (cols w*16..+15) and v.
        {
            const unsigned short* wbase = w_inp + (size_t)l * 49152;
            bf16x8 wq[4], wk[4], wv[4];
            #pragma unroll
            for (int ks = 0; ks < 4; ++ks) {
                wq[ks] = *(const bf16x8*)(wbase + (w * 16 + l15) * 128 + ks * 32 + kg * 8);
                wk[ks] = *(const bf16x8*)(wbase + (128 + w * 16 + l15) * 128 + ks * 32 + kg * 8);
                wv[ks] = *(const bf16x8*)(wbase + (256 + w * 16 + l15) * 128 + ks * 32 + kg * 8);
            }
            fx4 bq = *(const fx4*)(inp_b + l * 384 + w * 16 + kg * 4);
            fx4 bk = *(const fx4*)(inp_b + l * 384 + 128 + w * 16 + kg * 4);
            float bv = inp_b[l * 384 + 256 + w * 16 + l15];
            #pragma unroll
            for (int mt = 0; mt < 8; ++mt) {
                int trow = mt * 16 + l15;
                bf16x8 xf[4];
                #pragma unroll
                for (int ks = 0; ks < 4; ++ks)
                    xf[ks] = *(const bf16x8*)(xs + swz(trow, ks * 32 + kg * 8));
                fx4 aq = bq, ak = bk;
                fx4 av = {bv, bv, bv, bv};
                #pragma unroll
                for (int ks = 0; ks < 4; ++ks) {
                    aq = MFMA16(wq[ks], xf[ks], aq);   // Q^T = Wq * X^T
                    ak = MFMA16(wk[ks], xf[ks], ak);   // K^T = Wk * X^T
                    av = MFMA16(xf[ks], wv[ks], av);   // V   = X * Wv^T
                }
                ushort4 pq;  // q pre-scaled by 1/sqrt(HD)=0.25 (exact in bf16)
                pq.x = f2bf(aq[0] * 0.25f); pq.y = f2bf(aq[1] * 0.25f);
                pq.z = f2bf(aq[2] * 0.25f); pq.w = f2bf(aq[3] * 0.25f);
                *(ushort4*)(qs + swz(trow, w * 16 + kg * 4)) = pq;
                ushort4 pk4;
                pk4.x = f2bf(ak[0]); pk4.y = f2bf(ak[1]);
                pk4.z = f2bf(ak[2]); pk4.w = f2bf(ak[3]);
                *(ushort4*)(ksb + swz(trow, w * 16 + kg * 4)) = pk4;
                ushort4 pv4;
                pv4.x = f2bf(av[0]); pv4.y = f2bf(av[1]);
                pv4.z = f2bf(av[2]); pv4.w = f2bf(av[3]);
                *(ushort4*)(vtb + swz(w * 16 + l15, mt * 16 + kg * 4)) = pv4;
            }
        }
        // wave-local write->read: no barrier needed (wave w consumes only its
        // own head's q/k/v); just drain own DS queue.
        asm volatile("s_waitcnt lgkmcnt(0)" ::: "memory");

        // ========== Phase B: attention, wave w == head h (no barriers) ======
        {
            const int h = w;
            unsigned short* psw = ps + w * 1152;   // [16][72] P scratch
            // hoist K fragments (A-operand; kg==2 slot carries the mask,
            // kg==3 stays zero -> zero-padded K dims 17..31)
            bf16x8 kfr[8];
            #pragma unroll
            for (int kt = 0; kt < 8; ++kt) {
                bf16x8 f = {};
                if (kg < 2)
                    f = *(const bf16x8*)(ksb + swz(kt * 16 + l15, h * 16 + kg * 8));
                else if (kg == 2)
                    f[0] = (__bf16)mreg[kt];
                kfr[kt] = f;
            }
            // hoist V^T fragments (A-operand of PV)
            bf16x8 vfr[4];
            #pragma unroll
            for (int ks = 0; ks < 4; ++ks)
                vfr[ks] = *(const bf16x8*)(vtb + swz(h * 16 + l15, ks * 32 + kg * 8));

            for (int qt = 0; qt < 8; ++qt) {
                int qrow = qt * 16 + l15;
                bf16x8 qf = {};
                if (kg < 2)
                    qf = *(const bf16x8*)(qs + swz(qrow, h * 16 + kg * 8));
                else if (kg == 2)
                    qf[0] = (__bf16)1.0f;       // ones column -> adds mask
                // S^T tile: lane l15 = query, regs = 32 keys (scaled+masked)
                fx4 sc[8];
                #pragma unroll
                for (int kt = 0; kt < 8; ++kt) {
                    fx4 z = {0.f, 0.f, 0.f, 0.f};
                    sc[kt] = MFMA16(kfr[kt], qf, z);
                }
                // per-lane softmax over 32 regs, then 2 shuffles across kg
                float mx = -3.0e38f;
                #pragma unroll
                for (int kt = 0; kt < 8; ++kt)
                    #pragma unroll
                    for (int r = 0; r < 4; ++r) mx = fmaxf(mx, sc[kt][r]);
                mx = fmaxf(mx, __shfl_xor(mx, 16, 64));
                mx = fmaxf(mx, __shfl_xor(mx, 32, 64));
                float sm = 0.f;
                #pragma unroll
                for (int kt = 0; kt < 8; ++kt)
                    #pragma unroll
                    for (int r = 0; r < 4; ++r) {
                        float e = __expf(sc[kt][r] - mx);
                        sc[kt][r] = e;
                        sm += e;
                    }
                sm += __shfl_xor(sm, 16, 64);
                sm += __shfl_xor(sm, 32, 64);
                float inv = 1.f / sm;
                // P -> LDS (packed, [q][T] layout) in two 64-key chunks + PV
                fx4 oacc = {0.f, 0.f, 0.f, 0.f};
                #pragma unroll
                for (int ch = 0; ch < 2; ++ch) {
                    #pragma unroll
                    for (int k4 = 0; k4 < 4; ++k4) {
                        int kt = ch * 4 + k4;
                        ushort4 pp;
                        pp.x = f2bf(sc[kt][0] * inv); pp.y = f2bf(sc[kt][1] * inv);
                        pp.z = f2bf(sc[kt][2] * inv); pp.w = f2bf(sc[kt][3] * inv);
                        *(ushort4*)(psw + l15 * 72 + k4 * 16 + kg * 4) = pp;
                    }
                    asm volatile("s_waitcnt lgkmcnt(0)" ::: "memory");  // own-wave w->r
                    #pragma unroll
                    for (int k2 = 0; k2 < 2; ++k2) {
                        bf16x8 pf = *(const bf16x8*)(psw + l15 * 72 + k2 * 32 + kg * 8);
                        oacc = MFMA16(vfr[ch * 2 + k2], pf, oacc);  // O^T = V^T * P^T
                    }
                }
                // o tile packs as [t][d] ushort4; overwrites q rows of this qt
                ushort4 po;
                po.x = f2bf(oacc[0]); po.y = f2bf(oacc[1]);
                po.z = f2bf(oacc[2]); po.w = f2bf(oacc[3]);
                *(ushort4*)(qs + swz(qrow, h * 16 + kg * 4)) = po;
            }
        }
        __syncthreads();

        // ========= Phase C: out-proj (transposed) + residual + LN1 ==========
        {
            bf16x8 wof[4];
            #pragma unroll
            for (int ks = 0; ks < 4; ++ks)
                wof[ks] = *(const bf16x8*)(w_out + (size_t)(l * 128 + w * 16 + l15) * 128
                                           + ks * 32 + kg * 8);
            fx4 ob4 = *(const fx4*)(out_b + l * 128 + w * 16 + kg * 4);
            fx4 acc[8];
            #pragma unroll
            for (int tt = 0; tt < 8; ++tt) {
                int trow = tt * 16 + l15;
                fx4 a = {0.f, 0.f, 0.f, 0.f};
                #pragma unroll
                for (int ks = 0; ks < 4; ++ks) {
                    bf16x8 of = *(const bf16x8*)(qs + swz(trow, ks * 32 + kg * 8));
                    a = MFMA16(wof[ks], of, a);     // OUT^T = Wout * O^T
                }
                ushort4 rx = *(const ushort4*)(xs + swz(trow, w * 16 + kg * 4));
                a[0] += ob4[0] + bf2f(rx.x); a[1] += ob4[1] + bf2f(rx.y);
                a[2] += ob4[2] + bf2f(rx.z); a[3] += ob4[3] + bf2f(rx.w);
                acc[tt] = a;
                float s  = a[0] + a[1] + a[2] + a[3];
                float qq = a[0]*a[0] + a[1]*a[1] + a[2]*a[2] + a[3]*a[3];
                s  += __shfl_xor(s, 16, 64);  qq += __shfl_xor(qq, 16, 64);
                s  += __shfl_xor(s, 32, 64);  qq += __shfl_xor(qq, 32, 64);
                if (lid < 16) { float2 p; p.x = s; p.y = qq; lnp[w * 128 + trow] = p; }
            }
            __syncthreads();
            if (tid < 128) {
                float ms = 0.f, mq = 0.f;
                #pragma unroll
                for (int wv = 0; wv < 8; ++wv) {
                    float2 p = lnp[wv * 128 + tid];
                    ms += p.x; mq += p.y;
                }
                float mean = ms * 0.0078125f;
                float var  = mq * 0.0078125f - mean * mean;
                float2 m2; m2.x = mean; m2.y = rsqrtf(var + 1e-5f);
                mrp[tid] = m2;
            }
            __syncthreads();
            fx4 g4 = *(const fx4*)(ln1g + l * 128 + w * 16 + kg * 4);
            fx4 b4 = *(const fx4*)(ln1b + l * 128 + w * 16 + kg * 4);
            #pragma unroll
            for (int tt = 0; tt < 8; ++tt) {
                int trow = tt * 16 + l15;
                float2 m2 = mrp[trow];
                ushort4 px;
                px.x = f2bf((acc[tt][0] - m2.x) * m2.y * g4[0] + b4[0]);
                px.y = f2bf((acc[tt][1] - m2.x) * m2.y * g4[1] + b4[1]);
                px.z = f2bf((acc[tt][2] - m2.x) * m2.y * g4[2] + b4[2]);
                px.w = f2bf((acc[tt][3] - m2.x) * m2.y * g4[3] + b4[3]);
                *(ushort4*)(xs + swz(trow, w * 16 + kg * 4)) = px;
            }
        }
        __syncthreads();

        // ======== Phase D: FF, 2 K-chunks of 256; hidden aliases k|v^T ======
        fx4 yacc[8];
        {
            fx4 z = {0.f, 0.f, 0.f, 0.f};
            #pragma unroll
            for (int tt = 0; tt < 8; ++tt) yacc[tt] = z;
        }
        #pragma unroll
        for (int c = 0; c < 2; ++c) {
            {   // FF1: H^T = W1 * X^T, + bias + relu -> hidden (packed)
                bf16x8 w1f[2][4]; fx4 b1f[2];
                #pragma unroll
                for (int sub = 0; sub < 2; ++sub) {
                    int frow = l * 512 + c * 256 + sub * 128 + w * 16;
                    #pragma unroll
                    for (int ks = 0; ks < 4; ++ks)
                        w1f[sub][ks] = *(const bf16x8*)(w_ff1 + (size_t)(frow + l15) * 128
                                                        + ks * 32 + kg * 8);
                    b1f[sub] = *(const fx4*)(ff1b + frow + kg * 4);
                }
                #pragma unroll
                for (int tt = 0; tt < 8; ++tt) {
                    int trow = tt * 16 + l15;
                    bf16x8 xf[4];
                    #pragma unroll
                    for (int ks = 0; ks < 4; ++ks)
                        xf[ks] = *(const bf16x8*)(xs + swz(trow, ks * 32 + kg * 8));
                    #pragma unroll
                    for (int sub = 0; sub < 2; ++sub) {
                        fx4 a = b1f[sub];
                        #pragma unroll
                        for (int ks = 0; ks < 4; ++ks)
                            a = MFMA16(w1f[sub][ks], xf[ks], a);
                        ushort4 ph;
                        ph.x = f2bf(fmaxf(a[0], 0.f)); ph.y = f2bf(fmaxf(a[1], 0.f));
                        ph.z = f2bf(fmaxf(a[2], 0.f)); ph.w = f2bf(fmaxf(a[3], 0.f));
                        *(ushort4*)(kvh + swzh(trow, sub * 128 + w * 16 + kg * 4)) = ph;
                    }
                }
            }
            __syncthreads();
            {   // FF2 partial accumulate: Y^T = W2 * H^T
                bf16x8 w2f[8];
                #pragma unroll
                for (int k8 = 0; k8 < 8; ++k8)
                    w2f[k8] = *(const bf16x8*)(w_ff2 + (size_t)(l * 128 + w * 16 + l15) * 512
                                               + c * 256 + k8 * 32 + kg * 8);
                #pragma unroll
                for (int tt = 0; tt < 8; ++tt) {
                    int trow = tt * 16 + l15;
                    #pragma unroll
                    for (int k8 = 0; k8 < 8; ++k8) {
                        bf16x8 hf = *(const bf16x8*)(kvh + swzh(trow, k8 * 32 + kg * 8));
                        yacc[tt] = MFMA16(w2f[k8], hf, yacc[tt]);
                    }
                }
            }
            if (c == 0) __syncthreads();   // protect hidden before next chunk
        }

        // ========= Phase E: + bias + residual + LayerNorm2 (+ output) =======
        {
            fx4 fb4 = *(const fx4*)(ff2b + l * 128 + w * 16 + kg * 4);
            #pragma unroll
            for (int tt = 0; tt < 8; ++tt) {
                int trow = tt * 16 + l15;
                ushort4 rx = *(const ushort4*)(xs + swz(trow, w * 16 + kg * 4));
                yacc[tt][0] += fb4[0] + bf2f(rx.x);
                yacc[tt][1] += fb4[1] + bf2f(rx.y);
                yacc[tt][2] += fb4[2] + bf2f(rx.z);
                yacc[tt][3] += fb4[3] + bf2f(rx.w);
                fx4 a = yacc[tt];
                float s  = a[0] + a[1] + a[2] + a[3];
                float qq = a[0]*a[0] + a[1]*a[1] + a[2]*a[2] + a[3]*a[3];
                s  += __shfl_xor(s, 16, 64);  qq += __shfl_xor(qq, 16, 64);
                s  += __shfl_xor(s, 32, 64);  qq += __shfl_xor(qq, 32, 64);
                if (lid < 16) { float2 p; p.x = s; p.y = qq; lnp[w * 128 + trow] = p; }
            }
            __syncthreads();
            if (tid < 128) {
                float ms = 0.f, mq = 0.f;
                #pragma unroll
                for (int wv = 0; wv < 8; ++wv) {
                    float2 p = lnp[wv * 128 + tid];
                    ms += p.x; mq += p.y;
                }
                float mean = ms * 0.0078125f;
                float var  = mq * 0.0078125f - mean * mean;
                float2 m2; m2.x = mean; m2.y = rsqrtf(var + 1e-5f);
                mrp[tid] = m2;
            }
            __syncthreads();
            fx4 g4 = *(const fx4*)(ln2g + l * 128 + w * 16 + kg * 4);
            fx4 b4 = *(const fx4*)(ln2b + l * 128 + w * 16 + kg * 4);
            if (l == 1) {   // final layer: fp32 output, packed float4 stores
                float* op = out + (size_t)b * 16384;
                #pragma unroll
                for (int tt = 0; tt < 8; ++tt) {
                    int trow = tt * 16 + l15;
                    float2 m2 = mrp[trow];
                    float4 v4;
                    v4.x = (yacc[tt][0] - m2.x) * m2.y * g4[0] + b4[0];
                    v4.y = (yacc[tt][1] - m2.x) * m2.y * g4[1] + b4[1];
                    v4.z = (yacc[tt][2] - m2.x) * m2.y * g4[2] + b4[2];
                    v4.w = (yacc[tt][3] - m2.x) * m2.y * g4[3] + b4[3];
                    *(float4*)(op + (size_t)trow * 128 + w * 16 + kg * 4) = v4;
                }
            } else {
                #pragma unroll
                for (int tt = 0; tt < 8; ++tt) {
                    int trow = tt * 16 + l15;
                    float2 m2 = mrp[trow];
                    ushort4 px;
                    px.x = f2bf((yacc[tt][0] - m2.x) * m2.y * g4[0] + b4[0]);
                    px.y = f2bf((yacc[tt][1] - m2.x) * m2.y * g4[1] + b4[1]);
                    px.z = f2bf((yacc[tt][2] - m2.x) * m2.y * g4[2] + b4[2]);
                    px.w = f2bf((yacc[tt][3] - m2.x) * m2.y * g4[3] + b4[3]);
                    *(ushort4*)(xs + swz(trow, w * 16 + kg * 4)) = px;
                }
                __syncthreads();   // xs stable before next layer's Phase A
            }
        }
    }
}

// --------------------------------------------------------------------------
extern "C" void kernel_launch(void* const* d_in, const int* in_sizes, int n_in,
                              void* d_out, int out_size, void* d_ws, size_t ws_size,
                              hipStream_t stream) {
    const float* x    = (const float*)d_in[0];
    const float* mask = (const float*)d_in[1];
    const float* w_in = (const float*)d_in[2];
    const float* b_in = (const float*)d_in[3];
    const float* w_o  = (const float*)d_in[4];
    const float* b_o  = (const float*)d_in[5];
    const float* g1   = (const float*)d_in[6];
    const float* bb1  = (const float*)d_in[7];
    const float* w1   = (const float*)d_in[8];
    const float* b1   = (const float*)d_in[9];
    const float* w2   = (const float*)d_in[10];
    const float* b2   = (const float*)d_in[11];
    const float* g2   = (const float*)d_in[12];
    const float* bb2  = (const float*)d_in[13];

    unsigned short* ws = (unsigned short*)d_ws;   // bf16 weights, 786432 B
    prep_weights_bf16<<<1536, 256, 0, stream>>>(w_in, w_o, w1, w2, ws);
    fused_transformer<<<1024, 512, 0, stream>>>(
        x, mask, b_in, b_o, g1, bb1, b1, b2, g2, bb2,
        ws,                 // in_proj  [L][384][128]
        ws + 98304,         // out_w    [L][128][128]
        ws + 131072,        // ff1_w    [L][512][128]
        ws + 262144,        // ff2_w    [L][128][512]
        (float*)d_out);
}